// Round 8
// baseline (75.901 us; speedup 1.0000x reference)
//
#include <hip/hip_runtime.h>
#include <hip/hip_bf16.h>
#include <stdint.h>

// ElementReadoutMLP: species-routed 2-layer MLP, fused.
// Deterministic pipeline (no atomics, no memset):
//   bhist_k / scan_k / dscatter_k : countsort atoms by species (ballot-based);
//     scan_k also partitions gemm blocks across species (proportional, >=1).
//   convw_k : W1 [e][k][n] fp32 -> wt, PRE-SWIZZLED k-chunked bf16 layout
//   gemm_k  : PERSISTENT grouped GEMM, 256 blocks x 512 thr (1/CU), ONE
//             species per block -> B slice (32 cols x 256 k = 64 VGPRs)
//             loaded unconditionally ONCE, pinned live (launch_bounds 512,1
//             gives 256-VGPR cap so it stays resident).  Atom indices in LDS
//             (zero global vector loads in the loop).  A staged fp32 via
//             global_load_lds, 3-deep, counted vmcnt (T4).  Every wave
//             issues exactly 4 loads + 1 store per tile -> uniform vmcnt.
//             Fused bias+SiLU+W2-dot epilogue.

#define NDIM 256
#define CHUNKS 16      // scan chunks per species (NE*CHUNKS <= 256)
#define BCHUNK 16384   // bytes per B k-chunk (256 n x 32 k x 2B)
#define TROWS 32       // atoms per tile
#define ROWB 1040      // A row pitch bytes
#define MAXT 16        // max tiles per block (bounded ~13 for NE=10, NB=256)
#define NB_GEMM 256    // persistent gemm grid

typedef __attribute__((ext_vector_type(8))) short short8;
typedef __attribute__((ext_vector_type(8))) unsigned short ushort8;
typedef __attribute__((ext_vector_type(4))) float f32x4;

__device__ __forceinline__ unsigned short f2bf(float f) {
  unsigned u = __float_as_uint(f);
  u = (u + 0x7FFFu + ((u >> 16) & 1u)) >> 16;   // round-to-nearest-even
  return (unsigned short)u;
}

// async global->LDS, 16B per lane; lds dest must be wave-uniform base.
__device__ __forceinline__ void gload_lds16(const void* gsrc, void* ldst) {
  __builtin_amdgcn_global_load_lds(
      (const __attribute__((address_space(1))) unsigned*)gsrc,
      (__attribute__((address_space(3))) unsigned*)(uintptr_t)(unsigned)(uintptr_t)ldst,
      16, 0, 0);
}

// pack 8 fp32 -> short8 of bf16 (RNE, packed cvt)
__device__ __forceinline__ short8 cvt8(float4 lo, float4 hi) {
  union { short8 s; unsigned u[4]; } r;
  __hip_bfloat162 t;
  t = __float22bfloat162_rn(make_float2(lo.x, lo.y)); r.u[0] = *(unsigned*)&t;
  t = __float22bfloat162_rn(make_float2(lo.z, lo.w)); r.u[1] = *(unsigned*)&t;
  t = __float22bfloat162_rn(make_float2(hi.x, hi.y)); r.u[2] = *(unsigned*)&t;
  t = __float22bfloat162_rn(make_float2(hi.z, hi.w)); r.u[3] = *(unsigned*)&t;
  return r.s;
}

// ---- prep kernels -----------------------------------------------------------

// wt layout: chunk(e,step) = wt + (e*8+step)*BCHUNK bytes; within chunk,
// bf16 for (n,kk) at byte ((n*64 + kk*2) ^ ((n&7)<<4)).
__global__ void convw_k(const float* __restrict__ W1, unsigned short* __restrict__ wt, int NE) {
  int t = blockIdx.x * 256 + threadIdx.x;          // ((e*8+step)*4 + g)*256 + n
  if (t >= NE * 8192) return;
  int n = t & 255;
  int g = (t >> 8) & 3;            // kk-group of 8
  int step = (t >> 10) & 7;
  int e = t >> 13;
  int k0 = step * 32 + g * 8;
  const float* src = W1 + ((size_t)e << 16) + (size_t)k0 * NDIM + n;  // stride NDIM over j
  unsigned short v[8];
  #pragma unroll
  for (int j = 0; j < 8; ++j) v[j] = f2bf(src[j * NDIM]);
  char* chunk = (char*)wt + (size_t)(e * 8 + step) * BCHUNK;
  unsigned off = ((unsigned)(n * 64 + g * 16)) ^ ((unsigned)((n & 7) << 4));
  *(ushort8*)(chunk + off) = *(ushort8*)v;
}

// per-block histogram, deterministic (ballot-based, no atomics)
__global__ void bhist_k(const int* __restrict__ sp, int n, int* __restrict__ bc, int NE) {
  __shared__ int wc[4][16];
  int tid = threadIdx.x;
  int i = blockIdx.x * 256 + tid;
  int s = (i < n) ? sp[i] : -1;
  int w = tid >> 6, lane = tid & 63;
  for (int e = 0; e < NE; ++e) {
    unsigned long long m = __ballot(s == e);
    if (lane == 0) wc[w][e] = __popcll(m);
  }
  __syncthreads();
  if (tid < NE) bc[blockIdx.x * NE + tid] = wc[0][tid] + wc[1][tid] + wc[2][tid] + wc[3][tid];
}

// deterministic scan: blockCounts -> block offsets, species starts, tile
// offsets, and gemm block->species partition.
__global__ void scan_k(const int* __restrict__ bc, int* __restrict__ bo,
                       int* __restrict__ atom_start, int* __restrict__ tile_off,
                       int* __restrict__ bstart, int nblocks, int NE) {
  __shared__ int csum[256];
  __shared__ int coff[256];
  __shared__ int stot[16];
  __shared__ int sbase[16];
  int tid = threadIdx.x;
  int per = (nblocks + CHUNKS - 1) / CHUNKS;
  int e = tid / CHUNKS, c = tid % CHUNKS;
  int b0 = c * per, b1 = b0 + per; if (b1 > nblocks) b1 = nblocks;
  if (tid < NE * CHUNKS) {
    int s = 0;
    for (int b = b0; b < b1; ++b) s += bc[b * NE + e];
    csum[tid] = s;
  }
  __syncthreads();
  if (tid < NE) {
    int r = 0;
    for (int c2 = 0; c2 < CHUNKS; ++c2) { coff[tid * CHUNKS + c2] = r; r += csum[tid * CHUNKS + c2]; }
    stot[tid] = r;
  }
  __syncthreads();
  if (tid == 0) {
    int a = 0, t = 0;
    for (int e2 = 0; e2 < NE; ++e2) {
      sbase[e2] = a;
      atom_start[e2] = a; tile_off[e2] = t;
      a += stot[e2]; t += (stot[e2] + TROWS - 1) / TROWS;
    }
    atom_start[NE] = a; tile_off[NE] = t;
    // ---- partition NB_GEMM blocks across species, proportional, >=1 ----
    int ntl = t > 0 ? t : 1;
    int nbk[16]; int tot = 0, emax = 0;
    for (int e2 = 0; e2 < NE; ++e2) {
      int nt = tile_off[e2 + 1] - tile_off[e2];
      int v = (nt > 0) ? (int)(((long long)nt * NB_GEMM) / ntl) : 0;
      if (nt > 0 && v < 1) v = 1;
      nbk[e2] = v; tot += v;
      if (nbk[e2] > nbk[emax]) emax = e2;
    }
    nbk[emax] += NB_GEMM - tot;
    int bacc = 0;
    for (int e2 = 0; e2 < NE; ++e2) { bstart[e2] = bacc; bacc += nbk[e2]; }
    bstart[NE] = bacc;
  }
  __syncthreads();
  if (tid < NE * CHUNKS) {
    int run = sbase[e] + coff[tid];
    for (int b = b0; b < b1; ++b) { bo[b * NE + e] = run; run += bc[b * NE + e]; }
  }
}

// deterministic scatter: rank = block-offset + wave-prefix + lane-prefix
__global__ void dscatter_k(const int* __restrict__ sp, int n, const int* __restrict__ bo,
                           int* __restrict__ sorted, int NE) {
  __shared__ int wc[4][16];
  int tid = threadIdx.x;
  int i = blockIdx.x * 256 + tid;
  int s = (i < n) ? sp[i] : -1;
  int w = tid >> 6, lane = tid & 63;
  for (int e = 0; e < NE; ++e) {
    unsigned long long m = __ballot(s == e);
    if (lane == 0) wc[w][e] = __popcll(m);
  }
  __syncthreads();
  for (int e = 0; e < NE; ++e) {
    unsigned long long m = __ballot(s == e);
    if (s == e) {
      int wpre = 0;
      for (int w2 = 0; w2 < 4; ++w2) if (w2 < w) wpre += wc[w2][e];
      int rank = __popcll(m & ((1ull << lane) - 1ull));
      sorted[bo[blockIdx.x * NE + e] + wpre + rank] = i;
    }
  }
}

// ---- persistent fused grouped GEMM + SiLU + layer2 --------------------------

__global__ __launch_bounds__(512, 1) void gemm_k(
    const float* __restrict__ x, const unsigned short* __restrict__ wt,
    const float* __restrict__ b1, const float* __restrict__ w2,
    const float* __restrict__ b2, const int* __restrict__ sorted,
    const int* __restrict__ atom_start, const int* __restrict__ tile_off,
    const int* __restrict__ bstart, float* __restrict__ out, int NE)
{
  // LDS: A triple buffer 3 x 32 x 1040B = 99840 B + atom table + partials.
  // ~103 KB -> 1 block/CU, 8 waves.  VGPR cap 256 (launch_bounds 512,1):
  // B slice (64 VGPR) stays resident.
  __shared__ __align__(16) char ldsA[3][TROWS * ROWB];
  __shared__ float partLds[256];            // 8 waves x 32 rows
  __shared__ int ldsAtoms[MAXT * TROWS];    // block's atom indices (clamped)
  __shared__ int toffs[17], astart[17], bst[17];

  int tid = threadIdx.x, lane = tid & 63, wid = tid >> 6;   // wid 0..7
  int lr = lane & 15, lg = lane >> 4;

  if (tid <= NE) {
    toffs[tid] = tile_off[tid]; astart[tid] = atom_start[tid]; bst[tid] = bstart[tid];
  }
  __syncthreads();

  // ---- block -> (species, tile range); ONE species per block ----
  int b = blockIdx.x;
  int e = 0;
  while (b >= bst[e + 1]) ++e;
  int j = b - bst[e], nbe = bst[e + 1] - bst[e];
  int nte = toffs[e + 1] - toffs[e];
  int q = nte / nbe, r = nte % nbe;
  int cnt = q + (j < r ? 1 : 0);
  if (cnt <= 0) return;
  int t0 = toffs[e] + j * q + (j < r ? j : r);
  int t1 = t0 + cnt;

  // ---- cache atom indices in LDS (partial tiles clamp to last valid row) ----
  {
    int rs0 = astart[e] + (t0 - toffs[e]) * TROWS;
    int rvAll = astart[e + 1] - rs0;          // valid rows in this block's range
    for (int i = tid; i < cnt * TROWS; i += 512) {
      int rloc = (i < rvAll) ? i : (rvAll - 1);
      ldsAtoms[i] = sorted[rs0 + rloc];
    }
  }
  __syncthreads();

  // ---- B slice + layer params, loaded ONCE, unconditional ----
  short8 bf[2][8];
  float bbv[2], wvv[2];
  {
    const char* wbase = (const char*)wt + (size_t)e * 8 * BCHUNK;
    #pragma unroll
    for (int nf = 0; nf < 2; ++nf) {
      int ncol = wid * 32 + nf * 16 + lr;
      unsigned off = ((unsigned)(ncol * 64 + lg * 16)) ^ ((unsigned)((ncol & 7) << 4));
      #pragma unroll
      for (int s = 0; s < 8; ++s)
        bf[nf][s] = *(const short8*)(wbase + (size_t)s * BCHUNK + off);
      bbv[nf] = b1[(size_t)e * NDIM + ncol];
      wvv[nf] = w2[(size_t)e * NDIM + ncol];
    }
  }
  float b2v = b2[e];
  // pin B live in VGPRs (defeat load-sinking)
  #pragma unroll
  for (int nf = 0; nf < 2; ++nf)
    #pragma unroll
    for (int s = 0; s < 8; ++s)
      asm volatile("" :: "v"(bf[nf][s]));

  // stage: 4 rows/wave via global_load_lds; indices from LDS (lgkm only)
  auto stageA = [&](int t, int buf) {
    int base = (t - t0) * TROWS;
    #pragma unroll
    for (int i = 0; i < 4; ++i) {
      int rrow = wid * 4 + i;
      int atom = ldsAtoms[base + rrow];
      gload_lds16(x + (size_t)atom * NDIM + lane * 4, &ldsA[buf][rrow * ROWB]);
    }
  };

  // prologue: 2 tiles in flight (B loads drain under iter-t0's vmcnt(8))
  stageA(t0, 0);
  stageA(t0 + 1 < t1 ? t0 + 1 : t1 - 1, 1);

  for (int t = t0; t < t1; ++t) {
    int buf = (t - t0) % 3;

    // always issue exactly 4 stage loads (dummy at tail keeps count invariant)
    int ts = t + 2 < t1 ? t + 2 : t1 - 1;
    stageA(ts, (t - t0 + 2) % 3);

    // barrier1 (T4): counted vmcnt -- waits tile t's 4 loads only; the
    // 2-tiles-ahead DMA + prior stores stay in flight.  Every wave issues
    // exactly 4 loads + 1 store per iter -> counts uniform across waves.
    if (t == t0)          { asm volatile("s_waitcnt vmcnt(8)" ::: "memory"); }
    else if (t == t0 + 1) { asm volatile("s_waitcnt vmcnt(9)" ::: "memory"); }
    else                  { asm volatile("s_waitcnt vmcnt(10)" ::: "memory"); }
    __builtin_amdgcn_s_barrier();
    __builtin_amdgcn_sched_barrier(0);

    // ---- compute: 8 K-steps, no barriers, no global vector loads ----
    f32x4 acc[2][2];
    const f32x4 zero = {0.f, 0.f, 0.f, 0.f};
    #pragma unroll
    for (int i = 0; i < 2; ++i)
      #pragma unroll
      for (int jj = 0; jj < 2; ++jj) acc[i][jj] = zero;

    const char* Ab = ldsA[buf];
    #pragma unroll
    for (int step = 0; step < 8; ++step) {
      int k0 = step * 32;
      short8 af[2];
      #pragma unroll
      for (int mf = 0; mf < 2; ++mf) {
        const char* p = Ab + (mf * 16 + lr) * ROWB + (k0 + lg * 8) * 4;
        float4 lo = *(const float4*)p;
        float4 hi = *(const float4*)(p + 16);
        af[mf] = cvt8(lo, hi);
      }
      #pragma unroll
      for (int mf = 0; mf < 2; ++mf)
        #pragma unroll
        for (int nf = 0; nf < 2; ++nf)
          acc[mf][nf] = __builtin_amdgcn_mfma_f32_16x16x32_bf16(af[mf], bf[nf][step], acc[mf][nf], 0, 0, 0);
    }

    // ---- epilogue: +b1, SiLU, dot W2, reduce ----
    float psum[2][4];
    #pragma unroll
    for (int mf = 0; mf < 2; ++mf)
      #pragma unroll
      for (int rg = 0; rg < 4; ++rg) psum[mf][rg] = 0.f;

    #pragma unroll
    for (int nf = 0; nf < 2; ++nf) {
      #pragma unroll
      for (int mf = 0; mf < 2; ++mf)
        #pragma unroll
        for (int rg = 0; rg < 4; ++rg) {
          float h = acc[mf][nf][rg] + bbv[nf];
          float sv = h * __builtin_amdgcn_rcpf(1.f + __expf(-h));   // SiLU
          psum[mf][rg] += sv * wvv[nf];
        }
    }
    #pragma unroll
    for (int mf = 0; mf < 2; ++mf)
      #pragma unroll
      for (int rg = 0; rg < 4; ++rg) {
        float v = psum[mf][rg];
        v += __shfl_xor(v, 1, 64);
        v += __shfl_xor(v, 2, 64);
        v += __shfl_xor(v, 4, 64);
        v += __shfl_xor(v, 8, 64);
        psum[mf][rg] = v;
      }
    if (lr == 0) {
      #pragma unroll
      for (int mf = 0; mf < 2; ++mf)
        #pragma unroll
        for (int rg = 0; rg < 4; ++rg)
          partLds[wid * TROWS + mf * 16 + lg * 4 + rg] = psum[mf][rg];
    }

    // barrier2: LDS-only (lgkmcnt) -- prefetch DMA stays in flight.
    asm volatile("s_waitcnt lgkmcnt(0)" ::: "memory");
    __builtin_amdgcn_s_barrier();
    __builtin_amdgcn_sched_barrier(0);

    // out-store: EVERY wave stores 4 rows (lanes 0-3) -> uniform 1 VMEM/wave
    if (lane < 4) {
      int rloc = wid * 4 + lane;
      float s = b2v;
      #pragma unroll
      for (int w = 0; w < 8; ++w) s += partLds[w * TROWS + rloc];
      out[ldsAtoms[(t - t0) * TROWS + rloc]] = s;
    }
  }
}

// ---- launch -----------------------------------------------------------------

extern "C" void kernel_launch(void* const* d_in, const int* in_sizes, int n_in,
                              void* d_out, int out_size, void* d_ws, size_t ws_size,
                              hipStream_t stream) {
  const float* x  = (const float*)d_in[0];
  const int*   sp = (const int*)d_in[1];
  const float* W1 = (const float*)d_in[2];
  const float* b1 = (const float*)d_in[3];
  const float* W2 = (const float*)d_in[4];
  const float* b2 = (const float*)d_in[5];
  float* out = (float*)d_out;

  int n_atoms = in_sizes[0] / NDIM;
  int NE = in_sizes[2] / (NDIM * NDIM);
  int nblocks = (n_atoms + 255) / 256;

  // workspace layout (all 256-aligned); every word read is written this call.
  char* wsb = (char*)d_ws;
  size_t o = 0;
  int* bc = (int*)(wsb + o);         o += ((size_t)nblocks * NE * 4 + 255) & ~(size_t)255;
  int* bo = (int*)(wsb + o);         o += ((size_t)nblocks * NE * 4 + 255) & ~(size_t)255;
  int* atom_start = (int*)(wsb + o); o += 256;
  int* tile_off   = (int*)(wsb + o); o += 256;
  int* bstart     = (int*)(wsb + o); o += 256;
  int* sorted     = (int*)(wsb + o); o += ((size_t)n_atoms * 4 + 255) & ~(size_t)255;
  unsigned short* wt = (unsigned short*)(wsb + o);   // NE*128KB, 256-aligned

  hipLaunchKernelGGL(convw_k, dim3((NE * 8192 + 255) / 256), dim3(256), 0, stream,
                     W1, wt, NE);
  hipLaunchKernelGGL(bhist_k, dim3(nblocks), dim3(256), 0, stream, sp, n_atoms, bc, NE);
  hipLaunchKernelGGL(scan_k, dim3(1), dim3(256), 0, stream, bc, bo, atom_start, tile_off,
                     bstart, nblocks, NE);
  hipLaunchKernelGGL(dscatter_k, dim3(nblocks), dim3(256), 0, stream, sp, n_atoms, bo,
                     sorted, NE);

  hipLaunchKernelGGL(gemm_k, dim3(NB_GEMM), dim3(512), 0, stream,
                     x, wt, b1, W2, b2, sorted, atom_start, tile_off, bstart, out, NE);
}

// Round 9
// 69.974 us; speedup vs baseline: 1.0847x; 1.0847x over previous
//
#include <hip/hip_runtime.h>
#include <hip/hip_bf16.h>
#include <stdint.h>

// ElementReadoutMLP: species-routed 2-layer MLP, fused.
// Deterministic pipeline (no atomics, no memset):
//   bhist_k / scan_k / dscatter_k : countsort atoms by species (ballot-based);
//     scan_k also partitions gemm blocks across species (proportional, >=1).
//   convw_k : W1 [e][k][n] fp32 -> wt, PRE-SWIZZLED k-chunked bf16 layout
//   gemm_k  : PERSISTENT grouped GEMM, 512 blocks x 512 thr, ONE species per
//             block.  B slice (32 cols x 256 k = 64 VGPRs) loaded once,
//             pinned resident via "+v" asm.  A: reg-staged (4x float4
//             coalesced per thread), converted fp32->bf16 ONCE per element
//             (was 8x redundant per-wave), written to a 16KB swizzled bf16
//             LDS tile shared by all 8 waves.  Compute reads af as
//             ds_read_b128 directly.  Barriers are LDS-only; A prefetch for
//             t+1 issues mid-tile and rides in VGPRs across barriers (no
//             vmcnt drains anywhere).  Fused bias+SiLU+W2-dot epilogue.

#define NDIM 256
#define CHUNKS 16      // scan chunks per species (NE*CHUNKS <= 256)
#define BCHUNK 16384   // bytes per B k-chunk (256 n x 32 k x 2B)
#define TROWS 32       // atoms per tile
#define MAXT 16        // max tiles per block (cnt ~6-8 for NB=512)
#define NB_GEMM 512    // persistent gemm grid

typedef __attribute__((ext_vector_type(8))) short short8;
typedef __attribute__((ext_vector_type(8))) unsigned short ushort8;
typedef __attribute__((ext_vector_type(4))) float f32x4;
typedef __attribute__((ext_vector_type(2))) unsigned u32x2;

__device__ __forceinline__ unsigned short f2bf(float f) {
  unsigned u = __float_as_uint(f);
  u = (u + 0x7FFFu + ((u >> 16) & 1u)) >> 16;   // round-to-nearest-even
  return (unsigned short)u;
}

__device__ __forceinline__ unsigned pk2(float a, float b) {
  return (unsigned)f2bf(a) | ((unsigned)f2bf(b) << 16);
}

// ---- prep kernels -----------------------------------------------------------

// wt layout: chunk(e,step) = wt + (e*8+step)*BCHUNK bytes; within chunk,
// bf16 for (n,kk) at byte ((n*64 + kk*2) ^ ((n&7)<<4)).
__global__ void convw_k(const float* __restrict__ W1, unsigned short* __restrict__ wt, int NE) {
  int t = blockIdx.x * 256 + threadIdx.x;          // ((e*8+step)*4 + g)*256 + n
  if (t >= NE * 8192) return;
  int n = t & 255;
  int g = (t >> 8) & 3;            // kk-group of 8
  int step = (t >> 10) & 7;
  int e = t >> 13;
  int k0 = step * 32 + g * 8;
  const float* src = W1 + ((size_t)e << 16) + (size_t)k0 * NDIM + n;  // stride NDIM over j
  unsigned short v[8];
  #pragma unroll
  for (int j = 0; j < 8; ++j) v[j] = f2bf(src[j * NDIM]);
  char* chunk = (char*)wt + (size_t)(e * 8 + step) * BCHUNK;
  unsigned off = ((unsigned)(n * 64 + g * 16)) ^ ((unsigned)((n & 7) << 4));
  *(ushort8*)(chunk + off) = *(ushort8*)v;
}

// per-block histogram, deterministic (ballot-based, no atomics)
__global__ void bhist_k(const int* __restrict__ sp, int n, int* __restrict__ bc, int NE) {
  __shared__ int wc[4][16];
  int tid = threadIdx.x;
  int i = blockIdx.x * 256 + tid;
  int s = (i < n) ? sp[i] : -1;
  int w = tid >> 6, lane = tid & 63;
  for (int e = 0; e < NE; ++e) {
    unsigned long long m = __ballot(s == e);
    if (lane == 0) wc[w][e] = __popcll(m);
  }
  __syncthreads();
  if (tid < NE) bc[blockIdx.x * NE + tid] = wc[0][tid] + wc[1][tid] + wc[2][tid] + wc[3][tid];
}

// deterministic scan: blockCounts -> block offsets, species starts, tile
// offsets, and gemm block->species partition.
__global__ void scan_k(const int* __restrict__ bc, int* __restrict__ bo,
                       int* __restrict__ atom_start, int* __restrict__ tile_off,
                       int* __restrict__ bstart, int nblocks, int NE) {
  __shared__ int csum[256];
  __shared__ int coff[256];
  __shared__ int stot[16];
  __shared__ int sbase[16];
  int tid = threadIdx.x;
  int per = (nblocks + CHUNKS - 1) / CHUNKS;
  int e = tid / CHUNKS, c = tid % CHUNKS;
  int b0 = c * per, b1 = b0 + per; if (b1 > nblocks) b1 = nblocks;
  if (tid < NE * CHUNKS) {
    int s = 0;
    for (int b = b0; b < b1; ++b) s += bc[b * NE + e];
    csum[tid] = s;
  }
  __syncthreads();
  if (tid < NE) {
    int r = 0;
    for (int c2 = 0; c2 < CHUNKS; ++c2) { coff[tid * CHUNKS + c2] = r; r += csum[tid * CHUNKS + c2]; }
    stot[tid] = r;
  }
  __syncthreads();
  if (tid == 0) {
    int a = 0, t = 0;
    for (int e2 = 0; e2 < NE; ++e2) {
      sbase[e2] = a;
      atom_start[e2] = a; tile_off[e2] = t;
      a += stot[e2]; t += (stot[e2] + TROWS - 1) / TROWS;
    }
    atom_start[NE] = a; tile_off[NE] = t;
    // ---- partition NB_GEMM blocks across species, proportional, >=1 ----
    int ntl = t > 0 ? t : 1;
    int nbk[16]; int tot = 0, emax = 0;
    for (int e2 = 0; e2 < NE; ++e2) {
      int nt = tile_off[e2 + 1] - tile_off[e2];
      int v = (nt > 0) ? (int)(((long long)nt * NB_GEMM) / ntl) : 0;
      if (nt > 0 && v < 1) v = 1;
      nbk[e2] = v; tot += v;
      if (nbk[e2] > nbk[emax]) emax = e2;
    }
    nbk[emax] += NB_GEMM - tot;
    int bacc = 0;
    for (int e2 = 0; e2 < NE; ++e2) { bstart[e2] = bacc; bacc += nbk[e2]; }
    bstart[NE] = bacc;
  }
  __syncthreads();
  if (tid < NE * CHUNKS) {
    int run = sbase[e] + coff[tid];
    for (int b = b0; b < b1; ++b) { bo[b * NE + e] = run; run += bc[b * NE + e]; }
  }
}

// deterministic scatter: rank = block-offset + wave-prefix + lane-prefix
__global__ void dscatter_k(const int* __restrict__ sp, int n, const int* __restrict__ bo,
                           int* __restrict__ sorted, int NE) {
  __shared__ int wc[4][16];
  int tid = threadIdx.x;
  int i = blockIdx.x * 256 + tid;
  int s = (i < n) ? sp[i] : -1;
  int w = tid >> 6, lane = tid & 63;
  for (int e = 0; e < NE; ++e) {
    unsigned long long m = __ballot(s == e);
    if (lane == 0) wc[w][e] = __popcll(m);
  }
  __syncthreads();
  for (int e = 0; e < NE; ++e) {
    unsigned long long m = __ballot(s == e);
    if (s == e) {
      int wpre = 0;
      for (int w2 = 0; w2 < 4; ++w2) if (w2 < w) wpre += wc[w2][e];
      int rank = __popcll(m & ((1ull << lane) - 1ull));
      sorted[bo[blockIdx.x * NE + e] + wpre + rank] = i;
    }
  }
}

// ---- persistent fused grouped GEMM + SiLU + layer2 --------------------------

__global__ __launch_bounds__(512, 1) void gemm_k(
    const float* __restrict__ x, const unsigned short* __restrict__ wt,
    const float* __restrict__ b1, const float* __restrict__ w2,
    const float* __restrict__ b2, const int* __restrict__ sorted,
    const int* __restrict__ atom_start, const int* __restrict__ tile_off,
    const int* __restrict__ bstart, float* __restrict__ out, int NE)
{
  // LDS ~20 KB: bf16 A tile (32 x 512B, XOR-swizzled) + partials + atom table.
  __shared__ __align__(16) char ldsT[TROWS * 512];
  __shared__ float partLds[256];            // 8 waves x 32 rows
  __shared__ int ldsAtoms[MAXT * TROWS];
  __shared__ int toffs[17], astart[17], bst[17];

  int tid = threadIdx.x, lane = tid & 63, wid = tid >> 6;   // wid 0..7
  int lr = lane & 15, lg = lane >> 4;

  if (tid <= NE) {
    toffs[tid] = tile_off[tid]; astart[tid] = atom_start[tid]; bst[tid] = bstart[tid];
  }
  __syncthreads();

  // ---- block -> (species, tile range); ONE species per block ----
  int b = blockIdx.x;
  int e = 0;
  while (b >= bst[e + 1]) ++e;
  int j = b - bst[e], nbe = bst[e + 1] - bst[e];
  int nte = toffs[e + 1] - toffs[e];
  int q = nte / nbe, r = nte % nbe;
  int cnt = q + (j < r ? 1 : 0);
  if (cnt <= 0) return;
  if (cnt > MAXT) cnt = MAXT;   // unreachable at these sizes (cnt ~6-8)
  int t0 = toffs[e] + j * q + (j < r ? j : r);
  int t1 = t0 + cnt;

  // ---- cache atom indices in LDS (partial tiles clamp to last valid row) ----
  {
    int rs0 = astart[e] + (t0 - toffs[e]) * TROWS;
    int rvAll = astart[e + 1] - rs0;
    for (int i = tid; i < cnt * TROWS; i += 512) {
      int rloc = (i < rvAll) ? i : (rvAll - 1);
      ldsAtoms[i] = sorted[rs0 + rloc];
    }
  }
  __syncthreads();

  // ---- B slice + layer params, loaded ONCE, pinned resident ----
  short8 bf[2][8];
  float bbv[2], wvv[2];
  {
    const char* wbase = (const char*)wt + (size_t)e * 8 * BCHUNK;
    #pragma unroll
    for (int nf = 0; nf < 2; ++nf) {
      int ncol = wid * 32 + nf * 16 + lr;
      unsigned off = ((unsigned)(ncol * 64 + lg * 16)) ^ ((unsigned)((ncol & 7) << 4));
      #pragma unroll
      for (int s = 0; s < 8; ++s)
        bf[nf][s] = *(const short8*)(wbase + (size_t)s * BCHUNK + off);
      bbv[nf] = b1[(size_t)e * NDIM + ncol];
      wvv[nf] = w2[(size_t)e * NDIM + ncol];
    }
  }
  float b2v = b2[e];
  // read-write pins: compiler cannot rematerialize these from memory
  #pragma unroll
  for (int nf = 0; nf < 2; ++nf) {
    #pragma unroll
    for (int s = 0; s < 8; ++s) asm volatile("" : "+v"(bf[nf][s]));
    asm volatile("" : "+v"(bbv[nf]), "+v"(wvv[nf]));
  }

  // ---- A staging map: thread = (srow, skc); 4 coalesced float4/thread ----
  int srow = tid >> 4;          // 0..31 (atom row within tile)
  int skc  = tid & 15;          // 16 threads cover one 1KB row
  unsigned swzW = (unsigned)((srow & 7) << 4);
  unsigned rbW  = (unsigned)(srow * 512 + skc * 8);
  unsigned swzA = (unsigned)((lr & 7) << 4);   // (mf*16+lr)&7 == lr&7

  float4 xr0, xr1, xr2, xr3;
  {
    int atom = ldsAtoms[srow];
    const float* xp = x + (size_t)atom * NDIM + skc * 4;
    xr0 = *(const float4*)(xp);          // k-words kc*4 + 0..3   (j=0)
    xr1 = *(const float4*)(xp + 64);     // + j*64
    xr2 = *(const float4*)(xp + 128);
    xr3 = *(const float4*)(xp + 192);
  }

  for (int t = t0; t < t1; ++t) {
    // ---- cvt once + write swizzled bf16 tile ----
    {
      u32x2 w;
      w[0] = pk2(xr0.x, xr0.y); w[1] = pk2(xr0.z, xr0.w);
      *(u32x2*)(ldsT + ((rbW +   0) ^ swzW)) = w;
      w[0] = pk2(xr1.x, xr1.y); w[1] = pk2(xr1.z, xr1.w);
      *(u32x2*)(ldsT + ((rbW + 128) ^ swzW)) = w;
      w[0] = pk2(xr2.x, xr2.y); w[1] = pk2(xr2.z, xr2.w);
      *(u32x2*)(ldsT + ((rbW + 256) ^ swzW)) = w;
      w[0] = pk2(xr3.x, xr3.y); w[1] = pk2(xr3.z, xr3.w);
      *(u32x2*)(ldsT + ((rbW + 384) ^ swzW)) = w;
    }
    // ---- prefetch next tile's A into regs (hides under compute+epilogue) ----
    if (t + 1 < t1) {
      int atom = ldsAtoms[(t + 1 - t0) * TROWS + srow];
      const float* xp = x + (size_t)atom * NDIM + skc * 4;
      xr0 = *(const float4*)(xp);
      xr1 = *(const float4*)(xp + 64);
      xr2 = *(const float4*)(xp + 128);
      xr3 = *(const float4*)(xp + 192);
    }

    // barrier1: LDS-only; prefetch loads ride across in VGPR deps
    asm volatile("s_waitcnt lgkmcnt(0)" ::: "memory");
    __builtin_amdgcn_s_barrier();
    __builtin_amdgcn_sched_barrier(0);

    // ---- compute: 8 K-steps, bf16 af straight from LDS ----
    f32x4 acc[2][2];
    const f32x4 zero = {0.f, 0.f, 0.f, 0.f};
    #pragma unroll
    for (int i = 0; i < 2; ++i)
      #pragma unroll
      for (int jj = 0; jj < 2; ++jj) acc[i][jj] = zero;

    #pragma unroll
    for (int step = 0; step < 8; ++step) {
      short8 af[2];
      #pragma unroll
      for (int mf = 0; mf < 2; ++mf) {
        unsigned off = ((unsigned)((mf * 16 + lr) * 512 + step * 64 + lg * 16)) ^ swzA;
        af[mf] = *(const short8*)(ldsT + off);
      }
      #pragma unroll
      for (int mf = 0; mf < 2; ++mf)
        #pragma unroll
        for (int nf = 0; nf < 2; ++nf)
          acc[mf][nf] = __builtin_amdgcn_mfma_f32_16x16x32_bf16(af[mf], bf[nf][step], acc[mf][nf], 0, 0, 0);
    }

    // ---- epilogue: +b1, SiLU, dot W2, reduce ----
    float psum[2][4];
    #pragma unroll
    for (int mf = 0; mf < 2; ++mf)
      #pragma unroll
      for (int rg = 0; rg < 4; ++rg) psum[mf][rg] = 0.f;

    #pragma unroll
    for (int nf = 0; nf < 2; ++nf) {
      #pragma unroll
      for (int mf = 0; mf < 2; ++mf)
        #pragma unroll
        for (int rg = 0; rg < 4; ++rg) {
          float h = acc[mf][nf][rg] + bbv[nf];
          float sv = h * __builtin_amdgcn_rcpf(1.f + __expf(-h));   // SiLU
          psum[mf][rg] += sv * wvv[nf];
        }
    }
    #pragma unroll
    for (int mf = 0; mf < 2; ++mf)
      #pragma unroll
      for (int rg = 0; rg < 4; ++rg) {
        float v = psum[mf][rg];
        v += __shfl_xor(v, 1, 64);
        v += __shfl_xor(v, 2, 64);
        v += __shfl_xor(v, 4, 64);
        v += __shfl_xor(v, 8, 64);
        psum[mf][rg] = v;
      }
    if (lr == 0) {
      #pragma unroll
      for (int mf = 0; mf < 2; ++mf)
        #pragma unroll
        for (int rg = 0; rg < 4; ++rg)
          partLds[wid * TROWS + mf * 16 + lg * 4 + rg] = psum[mf][rg];
    }

    // barrier2: LDS-only; closes partLds writes AND tile reads (next iter's
    // cvt-writes are ordered after this barrier on every wave)
    asm volatile("s_waitcnt lgkmcnt(0)" ::: "memory");
    __builtin_amdgcn_s_barrier();
    __builtin_amdgcn_sched_barrier(0);

    // out-store: every wave stores 4 rows (lanes 0-3)
    if (lane < 4) {
      int rloc = wid * 4 + lane;
      float s = b2v;
      #pragma unroll
      for (int w = 0; w < 8; ++w) s += partLds[w * TROWS + rloc];
      out[ldsAtoms[(t - t0) * TROWS + rloc]] = s;
    }
  }
}

// ---- launch -----------------------------------------------------------------

extern "C" void kernel_launch(void* const* d_in, const int* in_sizes, int n_in,
                              void* d_out, int out_size, void* d_ws, size_t ws_size,
                              hipStream_t stream) {
  const float* x  = (const float*)d_in[0];
  const int*   sp = (const int*)d_in[1];
  const float* W1 = (const float*)d_in[2];
  const float* b1 = (const float*)d_in[3];
  const float* W2 = (const float*)d_in[4];
  const float* b2 = (const float*)d_in[5];
  float* out = (float*)d_out;

  int n_atoms = in_sizes[0] / NDIM;
  int NE = in_sizes[2] / (NDIM * NDIM);
  int nblocks = (n_atoms + 255) / 256;

  // workspace layout (all 256-aligned); every word read is written this call.
  char* wsb = (char*)d_ws;
  size_t o = 0;
  int* bc = (int*)(wsb + o);         o += ((size_t)nblocks * NE * 4 + 255) & ~(size_t)255;
  int* bo = (int*)(wsb + o);         o += ((size_t)nblocks * NE * 4 + 255) & ~(size_t)255;
  int* atom_start = (int*)(wsb + o); o += 256;
  int* tile_off   = (int*)(wsb + o); o += 256;
  int* bstart     = (int*)(wsb + o); o += 256;
  int* sorted     = (int*)(wsb + o); o += ((size_t)n_atoms * 4 + 255) & ~(size_t)255;
  unsigned short* wt = (unsigned short*)(wsb + o);   // NE*128KB, 256-aligned

  hipLaunchKernelGGL(convw_k, dim3((NE * 8192 + 255) / 256), dim3(256), 0, stream,
                     W1, wt, NE);
  hipLaunchKernelGGL(bhist_k, dim3(nblocks), dim3(256), 0, stream, sp, n_atoms, bc, NE);
  hipLaunchKernelGGL(scan_k, dim3(1), dim3(256), 0, stream, bc, bo, atom_start, tile_off,
                     bstart, nblocks, NE);
  hipLaunchKernelGGL(dscatter_k, dim3(nblocks), dim3(256), 0, stream, sp, n_atoms, bo,
                     sorted, NE);

  hipLaunchKernelGGL(gemm_k, dim3(NB_GEMM), dim3(512), 0, stream,
                     x, wt, b1, W2, b2, sorted, atom_start, tile_off, bstart, out, NE);
}

// Round 10
// 61.122 us; speedup vs baseline: 1.2418x; 1.1448x over previous
//
#include <hip/hip_runtime.h>
#include <hip/hip_bf16.h>
#include <stdint.h>

// ElementReadoutMLP: species-routed 2-layer MLP, fused.
// Deterministic pipeline (no atomics, no memset):
//   bhist_k / scan_k / dscatter_k : countsort atoms by species (ballot-based);
//     scan_k also partitions gemm blocks across species (proportional, >=1).
//   convw_k : W1 -> pre-swizzled bf16 wt via LDS transpose (coalesced reads)
//   gemm_k  : PERSISTENT grouped GEMM, 256 blocks x 512 thr, ONE species per
//             block, 64-atom tiles.  B slice (32 cols x 256 k = 64 VGPRs)
//             loaded once, pinned.  A reg-staged (coalesced), cvt once,
//             swizzled bf16 LDS tile.  MFMA called SWAPPED: D[n][atom] --
//             reduction over n is in-lane + 2 shfl_xor (was 32 ds_bpermute).
//             Barriers LDS-only; next tile's A prefetch rides in VGPRs.

#define NDIM 256
#define CHUNKS 16      // scan chunks per species (NE*CHUNKS <= 256)
#define BCHUNK 16384   // bytes per B k-chunk (256 n x 32 k x 2B)
#define TROWS 64       // atoms per tile
#define MAXT 16        // max tiles per block
#define NB_GEMM 256    // persistent gemm grid

typedef __attribute__((ext_vector_type(8))) short short8;
typedef __attribute__((ext_vector_type(8))) unsigned short ushort8;
typedef __attribute__((ext_vector_type(4))) float f32x4;
typedef __attribute__((ext_vector_type(2))) unsigned u32x2;

__device__ __forceinline__ unsigned short f2bf(float f) {
  unsigned u = __float_as_uint(f);
  u = (u + 0x7FFFu + ((u >> 16) & 1u)) >> 16;   // round-to-nearest-even
  return (unsigned short)u;
}

__device__ __forceinline__ unsigned pk2(float a, float b) {
  return (unsigned)f2bf(a) | ((unsigned)f2bf(b) << 16);
}

// ---- prep kernels -----------------------------------------------------------

// wt layout: chunk(e,step) = wt + (e*8+step)*BCHUNK bytes; within chunk,
// bf16 for (n,kk) at byte ((n*64 + kk*2) ^ ((n&7)<<4)).
// One block per (e,step): coalesced read of 32 k-rows into LDS, transpose,
// swizzled write.  (Old version did 655k stride-1KB scalar loads.)
__global__ void convw_k(const float* __restrict__ W1, unsigned short* __restrict__ wt, int NE) {
  __shared__ float ldsW[32 * 260];   // 32 k-rows x 256 n, pad 260 (bank spread)
  int blk = blockIdx.x;              // e*8 + step
  int e = blk >> 3, step = blk & 7;
  int tid = threadIdx.x;
  int k0 = step * 32;
  {
    int kk = tid >> 3, part = tid & 7;   // 8 threads cover one 1KB k-row
    const float* src = W1 + ((size_t)e << 16) + (size_t)(k0 + kk) * NDIM + part * 32;
    #pragma unroll
    for (int j = 0; j < 8; ++j) {
      float4 v = *(const float4*)(src + j * 4);
      *(float4*)&ldsW[kk * 260 + part * 32 + j * 4] = v;
    }
  }
  __syncthreads();
  {
    int n = tid;
    unsigned short v[32];
    #pragma unroll
    for (int kk = 0; kk < 32; ++kk) v[kk] = f2bf(ldsW[kk * 260 + n]);
    char* chunk = (char*)wt + (size_t)blk * BCHUNK;
    unsigned swz = (unsigned)((n & 7) << 4);
    #pragma unroll
    for (int g = 0; g < 4; ++g)
      *(ushort8*)(chunk + (((unsigned)(n * 64 + g * 16)) ^ swz)) = *(ushort8*)&v[g * 8];
  }
}

// per-block histogram, deterministic (ballot-based, no atomics)
__global__ void bhist_k(const int* __restrict__ sp, int n, int* __restrict__ bc, int NE) {
  __shared__ int wc[4][16];
  int tid = threadIdx.x;
  int i = blockIdx.x * 256 + tid;
  int s = (i < n) ? sp[i] : -1;
  int w = tid >> 6, lane = tid & 63;
  for (int e = 0; e < NE; ++e) {
    unsigned long long m = __ballot(s == e);
    if (lane == 0) wc[w][e] = __popcll(m);
  }
  __syncthreads();
  if (tid < NE) bc[blockIdx.x * NE + tid] = wc[0][tid] + wc[1][tid] + wc[2][tid] + wc[3][tid];
}

// deterministic scan: blockCounts -> block offsets, species starts, tile
// offsets, and gemm block->species partition.
__global__ void scan_k(const int* __restrict__ bc, int* __restrict__ bo,
                       int* __restrict__ atom_start, int* __restrict__ tile_off,
                       int* __restrict__ bstart, int nblocks, int NE) {
  __shared__ int csum[256];
  __shared__ int coff[256];
  __shared__ int stot[16];
  __shared__ int sbase[16];
  int tid = threadIdx.x;
  int per = (nblocks + CHUNKS - 1) / CHUNKS;
  int e = tid / CHUNKS, c = tid % CHUNKS;
  int b0 = c * per, b1 = b0 + per; if (b1 > nblocks) b1 = nblocks;
  if (tid < NE * CHUNKS) {
    int s = 0;
    for (int b = b0; b < b1; ++b) s += bc[b * NE + e];
    csum[tid] = s;
  }
  __syncthreads();
  if (tid < NE) {
    int r = 0;
    for (int c2 = 0; c2 < CHUNKS; ++c2) { coff[tid * CHUNKS + c2] = r; r += csum[tid * CHUNKS + c2]; }
    stot[tid] = r;
  }
  __syncthreads();
  if (tid == 0) {
    int a = 0, t = 0;
    for (int e2 = 0; e2 < NE; ++e2) {
      sbase[e2] = a;
      atom_start[e2] = a; tile_off[e2] = t;
      a += stot[e2]; t += (stot[e2] + TROWS - 1) / TROWS;
    }
    atom_start[NE] = a; tile_off[NE] = t;
    // ---- partition NB_GEMM blocks across species, proportional, >=1 ----
    int ntl = t > 0 ? t : 1;
    int nbk[16]; int tot = 0, emax = 0;
    for (int e2 = 0; e2 < NE; ++e2) {
      int nt = tile_off[e2 + 1] - tile_off[e2];
      int v = (nt > 0) ? (int)(((long long)nt * NB_GEMM) / ntl) : 0;
      if (nt > 0 && v < 1) v = 1;
      nbk[e2] = v; tot += v;
      if (nbk[e2] > nbk[emax]) emax = e2;
    }
    nbk[emax] += NB_GEMM - tot;
    int bacc = 0;
    for (int e2 = 0; e2 < NE; ++e2) { bstart[e2] = bacc; bacc += nbk[e2]; }
    bstart[NE] = bacc;
  }
  __syncthreads();
  if (tid < NE * CHUNKS) {
    int run = sbase[e] + coff[tid];
    for (int b = b0; b < b1; ++b) { bo[b * NE + e] = run; run += bc[b * NE + e]; }
  }
}

// deterministic scatter: rank = block-offset + wave-prefix + lane-prefix
__global__ void dscatter_k(const int* __restrict__ sp, int n, const int* __restrict__ bo,
                           int* __restrict__ sorted, int NE) {
  __shared__ int wc[4][16];
  int tid = threadIdx.x;
  int i = blockIdx.x * 256 + tid;
  int s = (i < n) ? sp[i] : -1;
  int w = tid >> 6, lane = tid & 63;
  for (int e = 0; e < NE; ++e) {
    unsigned long long m = __ballot(s == e);
    if (lane == 0) wc[w][e] = __popcll(m);
  }
  __syncthreads();
  for (int e = 0; e < NE; ++e) {
    unsigned long long m = __ballot(s == e);
    if (s == e) {
      int wpre = 0;
      for (int w2 = 0; w2 < 4; ++w2) if (w2 < w) wpre += wc[w2][e];
      int rank = __popcll(m & ((1ull << lane) - 1ull));
      sorted[bo[blockIdx.x * NE + e] + wpre + rank] = i;
    }
  }
}

// ---- persistent fused grouped GEMM + SiLU + layer2 --------------------------

__global__ __launch_bounds__(512, 1) void gemm_k(
    const float* __restrict__ x, const unsigned short* __restrict__ wt,
    const float* __restrict__ b1, const float* __restrict__ w2,
    const float* __restrict__ b2, const int* __restrict__ sorted,
    const int* __restrict__ atom_start, const int* __restrict__ tile_off,
    const int* __restrict__ bstart, float* __restrict__ out, int NE)
{
  // LDS ~39 KB: bf16 A tile (64 x 512B, XOR-swizzled) + partials + atoms.
  __shared__ __align__(16) char ldsT[TROWS * 512];
  __shared__ float partLds[8 * TROWS];      // 8 waves x 64 atoms
  __shared__ int ldsAtoms[MAXT * TROWS];
  __shared__ int toffs[17], astart[17], bst[17];

  int tid = threadIdx.x, lane = tid & 63, wid = tid >> 6;   // wid 0..7
  int lr = lane & 15, lg = lane >> 4;

  if (tid <= NE) {
    toffs[tid] = tile_off[tid]; astart[tid] = atom_start[tid]; bst[tid] = bstart[tid];
  }
  __syncthreads();

  // ---- block -> (species, tile range); ONE species per block ----
  int b = blockIdx.x;
  int e = 0;
  while (b >= bst[e + 1]) ++e;
  int j = b - bst[e], nbe = bst[e + 1] - bst[e];
  int nte = toffs[e + 1] - toffs[e];
  int q = nte / nbe, r = nte % nbe;
  int cnt = q + (j < r ? 1 : 0);
  if (cnt <= 0) return;
  if (cnt > MAXT) cnt = MAXT;   // unreachable at these sizes
  int t0 = toffs[e] + j * q + (j < r ? j : r);
  int t1 = t0 + cnt;

  // ---- cache atom indices in LDS (clamped -> benign duplicate writes) ----
  {
    int rs0 = astart[e] + (t0 - toffs[e]) * TROWS;
    int rvAll = astart[e + 1] - rs0;
    for (int i = tid; i < cnt * TROWS; i += 512) {
      int rloc = (i < rvAll) ? i : (rvAll - 1);
      ldsAtoms[i] = sorted[rs0 + rloc];
    }
  }
  __syncthreads();

  // ---- B slice + layer params, loaded ONCE, pinned resident ----
  short8 bf[2][8];
  float bbv[2][4], wvv[2][4];
  {
    const char* wbase = (const char*)wt + (size_t)e * 8 * BCHUNK;
    #pragma unroll
    for (int mf = 0; mf < 2; ++mf) {
      int ncol = wid * 32 + mf * 16 + lr;
      unsigned off = ((unsigned)(ncol * 64 + lg * 16)) ^ ((unsigned)((ncol & 7) << 4));
      #pragma unroll
      for (int s = 0; s < 8; ++s)
        bf[mf][s] = *(const short8*)(wbase + (size_t)s * BCHUNK + off);
      #pragma unroll
      for (int rg = 0; rg < 4; ++rg) {
        int n = wid * 32 + mf * 16 + lg * 4 + rg;   // swapped-layout n per lane
        bbv[mf][rg] = b1[(size_t)e * NDIM + n];
        wvv[mf][rg] = w2[(size_t)e * NDIM + n];
      }
    }
  }
  float b2v = b2[e];
  #pragma unroll
  for (int mf = 0; mf < 2; ++mf)
    #pragma unroll
    for (int s = 0; s < 8; ++s) asm volatile("" : "+v"(bf[mf][s]));

  // ---- A staging map: 8 threads per 1KB row, 8 float4 each, coalesced ----
  int srow = tid >> 3;          // 0..63
  int skc  = tid & 7;
  unsigned swzW = (unsigned)((srow & 7) << 4);
  float4 xr[8];
  {
    int atom = ldsAtoms[srow];
    const float* xp = x + (size_t)atom * NDIM + skc * 4;
    #pragma unroll
    for (int jj = 0; jj < 8; ++jj) xr[jj] = *(const float4*)(xp + jj * 32);
  }

  for (int t = t0; t < t1; ++t) {
    // ---- cvt once + write swizzled bf16 tile (k elems j*32+skc*4..+3) ----
    #pragma unroll
    for (int jj = 0; jj < 8; ++jj) {
      u32x2 w;
      w[0] = pk2(xr[jj].x, xr[jj].y); w[1] = pk2(xr[jj].z, xr[jj].w);
      *(u32x2*)(ldsT + (((unsigned)(srow * 512 + jj * 64 + skc * 8)) ^ swzW)) = w;
    }
    // ---- prefetch next tile's A into regs (hides under compute) ----
    if (t + 1 < t1) {
      int atom = ldsAtoms[(t + 1 - t0) * TROWS + srow];
      const float* xp = x + (size_t)atom * NDIM + skc * 4;
      #pragma unroll
      for (int jj = 0; jj < 8; ++jj) xr[jj] = *(const float4*)(xp + jj * 32);
    }

    asm volatile("s_waitcnt lgkmcnt(0)" ::: "memory");
    __builtin_amdgcn_s_barrier();
    __builtin_amdgcn_sched_barrier(0);

    // ---- compute: SWAPPED mfma -> acc[mf][nf] = D[n][atom] ----
    f32x4 acc[2][4];
    const f32x4 zero = {0.f, 0.f, 0.f, 0.f};
    #pragma unroll
    for (int i = 0; i < 2; ++i)
      #pragma unroll
      for (int jj = 0; jj < 4; ++jj) acc[i][jj] = zero;

    #pragma unroll
    for (int step = 0; step < 8; ++step) {
      short8 af[4];
      #pragma unroll
      for (int nf = 0; nf < 4; ++nf) {
        unsigned off = ((unsigned)((nf * 16 + lr) * 512 + step * 64 + lg * 16))
                     ^ ((unsigned)((lr & 7) << 4));
        af[nf] = *(const short8*)(ldsT + off);
      }
      #pragma unroll
      for (int mf = 0; mf < 2; ++mf)
        #pragma unroll
        for (int nf = 0; nf < 4; ++nf)
          acc[mf][nf] = __builtin_amdgcn_mfma_f32_16x16x32_bf16(bf[mf][step], af[nf], acc[mf][nf], 0, 0, 0);
    }

    // ---- epilogue: lane holds D[n = wid*32+mf*16+lg*4+rg][atom = nf*16+lr].
    // SiLU+w2-dot in-lane over (mf,rg); cross-lane reduce = 2 shfl_xor. ----
    float p[4];
    #pragma unroll
    for (int nf = 0; nf < 4; ++nf) {
      float s = 0.f;
      #pragma unroll
      for (int mf = 0; mf < 2; ++mf)
        #pragma unroll
        for (int rg = 0; rg < 4; ++rg) {
          float h = acc[mf][nf][rg] + bbv[mf][rg];
          s += h * __builtin_amdgcn_rcpf(1.f + __expf(-h)) * wvv[mf][rg];
        }
      s += __shfl_xor(s, 16, 64);
      s += __shfl_xor(s, 32, 64);
      p[nf] = s;
    }
    if (lg == 0) {
      #pragma unroll
      for (int nf = 0; nf < 4; ++nf)
        partLds[wid * TROWS + nf * 16 + lr] = p[nf];
    }

    asm volatile("s_waitcnt lgkmcnt(0)" ::: "memory");
    __builtin_amdgcn_s_barrier();
    __builtin_amdgcn_sched_barrier(0);

    if (tid < TROWS) {
      float s = b2v;
      #pragma unroll
      for (int w = 0; w < 8; ++w) s += partLds[w * TROWS + tid];
      out[ldsAtoms[(t - t0) * TROWS + tid]] = s;
    }
  }
}

// ---- launch -----------------------------------------------------------------

extern "C" void kernel_launch(void* const* d_in, const int* in_sizes, int n_in,
                              void* d_out, int out_size, void* d_ws, size_t ws_size,
                              hipStream_t stream) {
  const float* x  = (const float*)d_in[0];
  const int*   sp = (const int*)d_in[1];
  const float* W1 = (const float*)d_in[2];
  const float* b1 = (const float*)d_in[3];
  const float* W2 = (const float*)d_in[4];
  const float* b2 = (const float*)d_in[5];
  float* out = (float*)d_out;

  int n_atoms = in_sizes[0] / NDIM;
  int NE = in_sizes[2] / (NDIM * NDIM);
  int nblocks = (n_atoms + 255) / 256;

  // workspace layout (all 256-aligned); every word read is written this call.
  char* wsb = (char*)d_ws;
  size_t o = 0;
  int* bc = (int*)(wsb + o);         o += ((size_t)nblocks * NE * 4 + 255) & ~(size_t)255;
  int* bo = (int*)(wsb + o);         o += ((size_t)nblocks * NE * 4 + 255) & ~(size_t)255;
  int* atom_start = (int*)(wsb + o); o += 256;
  int* tile_off   = (int*)(wsb + o); o += 256;
  int* bstart     = (int*)(wsb + o); o += 256;
  int* sorted     = (int*)(wsb + o); o += ((size_t)n_atoms * 4 + 255) & ~(size_t)255;
  unsigned short* wt = (unsigned short*)(wsb + o);   // NE*128KB, 256-aligned

  hipLaunchKernelGGL(convw_k, dim3(NE * 8), dim3(256), 0, stream, W1, wt, NE);
  hipLaunchKernelGGL(bhist_k, dim3(nblocks), dim3(256), 0, stream, sp, n_atoms, bc, NE);
  hipLaunchKernelGGL(scan_k, dim3(1), dim3(256), 0, stream, bc, bo, atom_start, tile_off,
                     bstart, nblocks, NE);
  hipLaunchKernelGGL(dscatter_k, dim3(nblocks), dim3(256), 0, stream, sp, n_atoms, bo,
                     sorted, NE);

  hipLaunchKernelGGL(gemm_k, dim3(NB_GEMM), dim3(512), 0, stream,
                     x, wt, b1, W2, b2, sorted, atom_start, tile_off, bstart, out, NE);
}